// Round 4
// baseline (3085.033 us; speedup 1.0000x reference)
//
#include <hip/hip_runtime.h>
#include <hip/hip_bf16.h>
#include <stdint.h>

// ---------------------------------------------------------------------------
// Problem constants: B=16, N=1024, D=256, M=128, C=8192
// Inputs/outputs are fp32 (reference uses jnp.float32; confirmed by round-3
// forensics). Indices int32. Internal GEMMs run bf16 MFMA.
// Output: 3 x [B,N,D] fp32 concatenated.
// ---------------------------------------------------------------------------

namespace {
constexpr int B_ = 16;
constexpr int N_ = 1024;
constexpr int D_ = 256;
constexpr int M_ = 128;
constexpr int C_ = 8192;
constexpr int BN_ = B_ * N_;   // 16384
constexpr int CB_ = 4;         // attention S-chunk: batches per chunk
}

typedef short bf16x8_t __attribute__((ext_vector_type(8)));
typedef float f32x4_t __attribute__((ext_vector_type(4)));

#define DEV static __device__ __forceinline__

DEV unsigned short f2bf_bits(float x) {
    return __builtin_bit_cast(unsigned short, __float2bfloat16(x));
}

// fp32 -> bf16 conversion
__global__ void cvt_kernel(const float* __restrict__ src, __hip_bfloat16* __restrict__ dst, int n)
{
    const int i = blockIdx.x * 256 + threadIdx.x;
    if (i < n) dst[i] = __float2bfloat16(src[i]);
}

// ---------------------------------------------------------------------------
// Generic NT bf16 MFMA GEMM:  C[M,N] = scale * A[M,K] @ Bt[N,K]^T  (+ epilogue)
// 128x128 tile, BK=32, 256 threads = 4 waves (2x2 of 64x64), 16x16x32 mfma.
// epi: 0 = fp32 C = v*scale
//      1 = bf16 C = v + bias[col]                      (bias fp32)
//      2 = fp32 C[cOff+idx] = relu(v + bias[col] + addp[idx]); NaN->12345
//      3 = fp32 C = (accFlag ? C + v : v)
// Batched via blockIdx.z with element strides sA/sB/sC.
// Requires M%128==0, N%128==0, K%32==0.
// ---------------------------------------------------------------------------
__global__ __launch_bounds__(256) void gemm_nt_kernel(
    const __hip_bfloat16* __restrict__ Abf, int lda, long long sA,
    const __hip_bfloat16* __restrict__ Btbf, int ldb, long long sB,
    void* __restrict__ Cv, int ldc, long long sC, long long cOff,
    int K, float scale,
    const float* __restrict__ bias,
    const float* __restrict__ addp,
    int epi, int accFlag)
{
    __shared__ __align__(16) short smA[128 * 32];
    __shared__ __align__(16) short smB[128 * 32];

    const int tid = threadIdx.x;
    const int wid = tid >> 6;
    const int lane = tid & 63;
    const size_t bz = blockIdx.z;

    const short* Ab = (const short*)Abf + bz * (size_t)sA + (size_t)blockIdx.x * 128 * lda;
    const short* Bb = (const short*)Btbf + bz * (size_t)sB + (size_t)blockIdx.y * 128 * ldb;

    const int wm = (wid >> 1) * 64;
    const int wn = (wid & 1) * 64;
    const int fr = lane & 15;            // fragment row (m or n)
    const int kq = (lane >> 4) * 8;      // k-offset of this lane's 8 elems
    const int sr = tid >> 2;             // staging row 0..63 (plus h*64)
    const int sc = (tid & 3) * 8;        // staging short-col

    f32x4_t acc[4][4] = {};

    for (int k0 = 0; k0 < K; k0 += 32) {
        int4 avv[2], bvv[2];
#pragma unroll
        for (int h = 0; h < 2; h++) {
            const int row = h * 64 + sr;
            avv[h] = *(const int4*)(Ab + (size_t)row * lda + (k0 + sc));
            bvv[h] = *(const int4*)(Bb + (size_t)row * ldb + (k0 + sc));
        }
        __syncthreads();
#pragma unroll
        for (int h = 0; h < 2; h++) {
            const int row = h * 64 + sr;
            *(int4*)&smA[row * 32 + sc] = avv[h];
            *(int4*)&smB[row * 32 + sc] = bvv[h];
        }
        __syncthreads();

        bf16x8_t af[4], bfv[4];
#pragma unroll
        for (int i = 0; i < 4; i++)
            af[i] = *(const bf16x8_t*)&smA[(wm + i * 16 + fr) * 32 + kq];
#pragma unroll
        for (int j = 0; j < 4; j++)
            bfv[j] = *(const bf16x8_t*)&smB[(wn + j * 16 + fr) * 32 + kq];
#pragma unroll
        for (int i = 0; i < 4; i++)
#pragma unroll
            for (int j = 0; j < 4; j++)
                acc[i][j] = __builtin_amdgcn_mfma_f32_16x16x32_bf16(af[i], bfv[j], acc[i][j], 0, 0, 0);
    }

    const int rb = (lane >> 4) * 4;
#pragma unroll
    for (int j = 0; j < 4; j++) {
        const int col = blockIdx.y * 128 + wn + j * 16 + fr;
        const float bv = bias ? bias[col] : 0.0f;
#pragma unroll
        for (int i = 0; i < 4; i++) {
#pragma unroll
            for (int r = 0; r < 4; r++) {
                const int row = blockIdx.x * 128 + wm + i * 16 + rb + r;
                const size_t idx = bz * (size_t)sC + (size_t)row * ldc + col;
                const float v = acc[i][j][r] * scale;
                if (epi == 0) {
                    ((float*)Cv)[idx] = v;
                } else if (epi == 1) {
                    ((__hip_bfloat16*)Cv)[idx] = __float2bfloat16(v + bv);
                } else if (epi == 2) {
                    float o = v + bv + addp[idx];
                    float rr = o > 0.0f ? o : 0.0f;
                    if (!(o == o)) rr = 12345.0f;     // NaN sentinel (debug)
                    ((float*)Cv)[(size_t)cOff + idx] = rr;
                } else {
                    float* Cf = (float*)Cv;
                    Cf[idx] = accFlag ? (Cf[idx] + v) : v;
                }
            }
        }
    }
}

// ---------------------------------------------------------------------------
// Weight convert+transpose: Wt[d][k] (bf16) = W[k][d] (fp32). grid(8,8).
// ---------------------------------------------------------------------------
__global__ __launch_bounds__(256) void wt_transpose_kernel(
    const float* __restrict__ in, __hip_bfloat16* __restrict__ out)
{
    __shared__ float t[32][33];
    const int r0 = blockIdx.x * 32, c0 = blockIdx.y * 32;
    const int tx = threadIdx.x & 31, ty = threadIdx.x >> 5;
#pragma unroll
    for (int k = 0; k < 4; k++) {
        int r = ty + k * 8;
        t[r][tx] = in[(size_t)(r0 + r) * D_ + (c0 + tx)];
    }
    __syncthreads();
#pragma unroll
    for (int k = 0; k < 4; k++) {
        int r = ty + k * 8;
        out[(size_t)(c0 + r) * D_ + (r0 + tx)] = __float2bfloat16(t[tx][r]);
    }
}

// ---------------------------------------------------------------------------
// bf16 transpose (for V): out[c][r] = in[r][c], batched.
// ---------------------------------------------------------------------------
__global__ __launch_bounds__(256) void transpose_bf16_kernel(
    const __hip_bfloat16* __restrict__ in, __hip_bfloat16* __restrict__ out,
    int R, int Cc, long long sIn, long long sOut)
{
    __shared__ short t[32][33];
    const size_t bz = blockIdx.z;
    const short* I = (const short*)in + bz * (size_t)sIn;
    short* O = (short*)out + bz * (size_t)sOut;
    const int r0 = blockIdx.x * 32, c0 = blockIdx.y * 32;
    const int tx = threadIdx.x & 31, ty = threadIdx.x >> 5;
#pragma unroll
    for (int k = 0; k < 4; k++) {
        int r = ty + k * 8;
        t[r][tx] = I[(size_t)(r0 + r) * Cc + (c0 + tx)];
    }
    __syncthreads();
#pragma unroll
    for (int k = 0; k < 4; k++) {
        int r = ty + k * 8;
        O[(size_t)(c0 + r) * R + (r0 + tx)] = t[tx][r];
    }
}

__global__ void zero_kernel(float* __restrict__ p, int n)
{
    const int i = blockIdx.x * 256 + threadIdx.x;
    if (i < n) p[i] = 0.0f;
}

// ---------------------------------------------------------------------------
// Hypergraph helpers (all fp32 internal)
// ---------------------------------------------------------------------------
__global__ void hg_count_kernel(const int* __restrict__ nidx, const int* __restrict__ eidx,
                                int* __restrict__ Ddeg, int* __restrict__ Edeg)
{
    const int c = blockIdx.x * 256 + threadIdx.x;
    atomicAdd(&Ddeg[nidx[c]], 1);
    atomicAdd(&Edeg[eidx[c]], 1);
}

__global__ __launch_bounds__(1024) void hg_scan_kernel(
    const int* __restrict__ deg, int* __restrict__ offs,
    float* __restrict__ inv, int* __restrict__ cnt, int len)
{
    __shared__ int tmp[1024];
    const int t = threadIdx.x;
    const int v = deg[t];
    tmp[t] = v;
    __syncthreads();
    for (int o = 1; o < len; o <<= 1) {
        int x = (t >= o) ? tmp[t - o] : 0;
        __syncthreads();
        tmp[t] += x;
        __syncthreads();
    }
    offs[t] = tmp[t] - v;
    if (t == len - 1) offs[len] = tmp[t];
    inv[t] = (v > 0) ? (1.0f / (float)v) : 0.0f;
    cnt[t] = 0;
}

__global__ void hg_fill_kernel(const int* __restrict__ nidx, const int* __restrict__ eidx,
                               const int* __restrict__ noffs, const int* __restrict__ eoffs,
                               int* __restrict__ ncnt, int* __restrict__ ecnt,
                               int* __restrict__ nord, int* __restrict__ eord)
{
    const int c = blockIdx.x * 256 + threadIdx.x;
    const int nd = nidx[c], ed = eidx[c];
    const int p1 = atomicAdd(&ncnt[nd], 1);
    nord[noffs[nd] + p1] = c;
    const int p2 = atomicAdd(&ecnt[ed], 1);
    eord[eoffs[ed] + p2] = c;
}

// s1[n,b] = xp[b,n,:].att[:D], s2 = xp[b,n,:].att[D:]. one wave per (b,n).
__global__ __launch_bounds__(64) void hg_s12_kernel(
    const float* __restrict__ xp, const float* __restrict__ att,
    float* __restrict__ s1, float* __restrict__ s2)
{
    const int bid = blockIdx.x;
    const int b = bid >> 10;
    const int n = bid & (N_ - 1);
    const int lane = threadIdx.x;
    const float4 xv = ((const float4*)(xp + ((size_t)(b * N_ + n)) * D_))[lane];
    const float4 a1 = ((const float4*)att)[lane];
    const float4 a2 = ((const float4*)(att + D_))[lane];
    float d1 = xv.x * a1.x + xv.y * a1.y + xv.z * a1.z + xv.w * a1.w;
    float d2 = xv.x * a2.x + xv.y * a2.y + xv.z * a2.z + xv.w * a2.w;
#pragma unroll
    for (int o = 32; o > 0; o >>= 1) { d1 += __shfl_down(d1, o); d2 += __shfl_down(d2, o); }
    if (lane == 0) { s1[n * 16 + b] = d1; s2[n * 16 + b] = d2; }
}

__global__ void hg_edge_s2_kernel(const int* __restrict__ nidx, const int* __restrict__ eidx,
                                  const float* __restrict__ s2, float* __restrict__ edge_s2)
{
    const int i = blockIdx.x * 256 + threadIdx.x;   // C*B
    const int c = i >> 4, b = i & 15;
    atomicAdd(&edge_s2[eidx[c] * 16 + b], s2[nidx[c] * 16 + b]);
}

__global__ __launch_bounds__(256) void hg_node_softmax_kernel(
    const int* __restrict__ eidx, const int* __restrict__ noffs,
    const int* __restrict__ nord, const float* __restrict__ s1,
    const float* __restrict__ edge_s2, float* __restrict__ ee,
    float* __restrict__ inv_sum)
{
    const int n = blockIdx.x;
    const int base = noffs[n];
    const int len = noffs[n + 1] - base;
    if (len == 0) return;
    const int cp = threadIdx.x >> 4;
    const int b = threadIdx.x & 15;
    __shared__ float red[16][16];
    const float s1nb = s1[n * 16 + b];

    float mx = -1e30f;
    for (int i = cp; i < len; i += 16) {
        int c = nord[base + i];
        float e = s1nb + edge_s2[eidx[c] * 16 + b];
        e = e > 0.0f ? e : 0.2f * e;      // leaky_relu 0.2
        mx = fmaxf(mx, e);
    }
    red[cp][b] = mx;
    __syncthreads();
    for (int s = 8; s > 0; s >>= 1) {
        if (cp < s) red[cp][b] = fmaxf(red[cp][b], red[cp + s][b]);
        __syncthreads();
    }
    mx = red[0][b];
    __syncthreads();

    float sm = 0.0f;
    for (int i = cp; i < len; i += 16) {
        int c = nord[base + i];
        float e = s1nb + edge_s2[eidx[c] * 16 + b];
        e = e > 0.0f ? e : 0.2f * e;
        float ex = __expf(e - mx);
        ee[c * 16 + b] = ex;
        sm += ex;
    }
    red[cp][b] = sm;
    __syncthreads();
    for (int s = 8; s > 0; s >>= 1) {
        if (cp < s) red[cp][b] += red[cp + s][b];
        __syncthreads();
    }
    if (cp == 0) inv_sum[n * 16 + b] = 1.0f / (red[0][b] + 1e-16f);
}

__global__ __launch_bounds__(256) void hg_xedge_kernel(
    const int* __restrict__ nidx, const int* __restrict__ eoffs,
    const int* __restrict__ eord, const float* __restrict__ ee,
    const float* __restrict__ inv_sum, const float* __restrict__ xp,
    const float* __restrict__ Bnorm, float* __restrict__ x_edge)
{
    const int m = blockIdx.x >> 4;
    const int b = blockIdx.x & 15;
    const int d = threadIdx.x;
    const int base = eoffs[m];
    const int len = eoffs[m + 1] - base;
    float acc = 0.0f;
    for (int i = 0; i < len; i++) {
        int c = eord[base + i];
        int nd = nidx[c];
        float coeff = ee[c * 16 + b] * inv_sum[nd * 16 + b];
        acc += coeff * xp[((size_t)(b * N_ + nd)) * D_ + d];
    }
    x_edge[((size_t)(m * 16 + b)) * D_ + d] = Bnorm[m] * acc;
}

__global__ __launch_bounds__(256) void hg_xnode_kernel(
    const int* __restrict__ eidx, const int* __restrict__ noffs,
    const int* __restrict__ nord, const float* __restrict__ ee,
    const float* __restrict__ inv_sum, const float* __restrict__ x_edge,
    const float* __restrict__ Dinv, __hip_bfloat16* __restrict__ hbf)
{
    const int n = blockIdx.x >> 4;
    const int b = blockIdx.x & 15;
    const int d = threadIdx.x;
    const int base = noffs[n];
    const int len = noffs[n + 1] - base;
    float acc = 0.0f;
    const float inv = (len > 0) ? inv_sum[n * 16 + b] : 0.0f;
    for (int i = 0; i < len; i++) {
        int c = nord[base + i];
        float coeff = ee[c * 16 + b] * inv;
        acc += coeff * x_edge[((size_t)(eidx[c] * 16 + b)) * D_ + d];
    }
    hbf[((size_t)(b * N_ + n)) * D_ + d] = __float2bfloat16(Dinv[n] * acc);
}

// ---------------------------------------------------------------------------
// Row softmax over S (fp32, 1024 cols), bf16 P written in place.
// ---------------------------------------------------------------------------
__global__ __launch_bounds__(256) void attn_softmax_kernel(float* __restrict__ S)
{
    const int row = blockIdx.x;
    float* srow = S + (size_t)row * 1024;
    const int tid = threadIdx.x;
    const int lane = tid & 63, wid = tid >> 6;
    const float4 v = ((const float4*)srow)[tid];
    __shared__ float red[8];

    float m4 = fmaxf(fmaxf(v.x, v.y), fmaxf(v.z, v.w));
#pragma unroll
    for (int o = 32; o > 0; o >>= 1) m4 = fmaxf(m4, __shfl_down(m4, o));
    if (lane == 0) red[wid] = m4;
    __syncthreads();
    const float mx = fmaxf(fmaxf(red[0], red[1]), fmaxf(red[2], red[3]));

    const float e0 = __expf(v.x - mx), e1 = __expf(v.y - mx);
    const float e2 = __expf(v.z - mx), e3 = __expf(v.w - mx);
    float s4 = e0 + e1 + e2 + e3;
#pragma unroll
    for (int o = 32; o > 0; o >>= 1) s4 += __shfl_down(s4, o);
    if (lane == 0) red[4 + wid] = s4;
    __syncthreads();
    const float inv = 1.0f / (red[4] + red[5] + red[6] + red[7]);

    ushort4 pk;
    pk.x = f2bf_bits(e0 * inv);
    pk.y = f2bf_bits(e1 * inv);
    pk.z = f2bf_bits(e2 * inv);
    pk.w = f2bf_bits(e3 * inv);
    ((ushort4*)srow)[tid] = pk;
}

// ---------------------------------------------------------------------------
// Host
// ---------------------------------------------------------------------------
static inline void launch_gemm(hipStream_t s,
                               const void* A, int lda, long long sA,
                               const void* Bt, int ldb, long long sB,
                               void* Cv, int ldc, long long sC, long long cOff,
                               int Mrows, int Ncols, int K, int batches,
                               float scale, const float* bias, const float* addp,
                               int epi, int accFlag)
{
    dim3 g(Mrows / 128, Ncols / 128, batches);
    gemm_nt_kernel<<<g, 256, 0, s>>>((const __hip_bfloat16*)A, lda, sA,
                                     (const __hip_bfloat16*)Bt, ldb, sB,
                                     Cv, ldc, sC, cOff, K, scale,
                                     bias, addp, epi, accFlag);
}

extern "C" void kernel_launch(void* const* d_in, const int* in_sizes, int n_in,
                              void* d_out, int out_size, void* d_ws, size_t ws_size,
                              hipStream_t stream)
{
    (void)in_sizes; (void)n_in; (void)out_size; (void)ws_size;

    const float* xin[3] = {(const float*)d_in[0], (const float*)d_in[1], (const float*)d_in[2]};
    const int* hidx[3] = {(const int*)d_in[3], (const int*)d_in[4], (const int*)d_in[5]};
    const float* W_hg  = (const float*)d_in[6];
    const float* att_hg= (const float*)d_in[7];
    const float* WQ = (const float*)d_in[8];
    const float* bQ = (const float*)d_in[9];
    const float* WK = (const float*)d_in[10];
    const float* bK = (const float*)d_in[11];
    const float* WV = (const float*)d_in[12];
    const float* bV = (const float*)d_in[13];
    const float* WO = (const float*)d_in[14];
    const float* bO = (const float*)d_in[15];
    float* outp = (float*)d_out;

    char* ws = (char*)d_ws;
    size_t off = 0;
    auto take = [&](size_t bytes) { size_t r = off; off += (bytes + 255) & ~(size_t)255; return r; };

    const size_t oWt   = take((size_t)5 * D_ * D_ * 2);
    const size_t oHbf  = take((size_t)3 * BN_ * D_ * 2);       // 24 MB
    const size_t oKbf  = take((size_t)3 * BN_ * D_ * 2);       // 24 MB
    const size_t oVt   = take((size_t)3 * BN_ * D_ * 2);       // 24 MB
    const size_t oQbf  = take((size_t)BN_ * D_ * 2);           // 8 MB
    const size_t oTmp  = take((size_t)BN_ * D_ * 2);           // 8 MB: Xc / Vtmp
    const size_t oMsg  = take((size_t)BN_ * D_ * 4);           // 16 MB
    const size_t oR1   = take((size_t)BN_ * D_ * 4);           // 16 MB: Xp / S-chunk
    const size_t oXe   = take((size_t)M_ * B_ * D_ * 4);
    const size_t oEE   = take((size_t)C_ * B_ * 4);
    const size_t oS1   = take((size_t)N_ * B_ * 4);
    const size_t oS2   = take((size_t)N_ * B_ * 4);
    const size_t oInv  = take((size_t)N_ * B_ * 4);
    const size_t oZero = take((size_t)(N_ * 4 + M_ * 4 + M_ * B_ * 4));
    const size_t oNOffs= take((size_t)(N_ + 1) * 4);
    const size_t oEOffs= take((size_t)(M_ + 1) * 4);
    const size_t oNCnt = take((size_t)N_ * 4);
    const size_t oECnt = take((size_t)M_ * 4);
    const size_t oNOrd = take((size_t)C_ * 4);
    const size_t oEOrd = take((size_t)C_ * 4);
    const size_t oDinv = take((size_t)N_ * 4);
    const size_t oBnorm= take((size_t)M_ * 4);

    __hip_bfloat16* Wt   = (__hip_bfloat16*)(ws + oWt);
    __hip_bfloat16* Hbf  = (__hip_bfloat16*)(ws + oHbf);
    __hip_bfloat16* Kbf  = (__hip_bfloat16*)(ws + oKbf);
    __hip_bfloat16* Vt   = (__hip_bfloat16*)(ws + oVt);
    __hip_bfloat16* Qbf  = (__hip_bfloat16*)(ws + oQbf);
    __hip_bfloat16* Tmp  = (__hip_bfloat16*)(ws + oTmp);   // Xc (phase1) / Vtmp (phase2)
    float* Msg  = (float*)(ws + oMsg);
    float* Xp   = (float*)(ws + oR1);
    float* Sf   = (float*)(ws + oR1);
    float* Xe   = (float*)(ws + oXe);
    float* EE   = (float*)(ws + oEE);
    float* S1   = (float*)(ws + oS1);
    float* S2   = (float*)(ws + oS2);
    float* Inv  = (float*)(ws + oInv);
    int*   Ddeg = (int*)(ws + oZero);
    int*   Edeg = (int*)(ws + oZero + (size_t)N_ * 4);
    float* Es2  = (float*)(ws + oZero + (size_t)N_ * 4 + (size_t)M_ * 4);
    const int zeroWords = N_ + M_ + M_ * B_;
    int*   NOffs = (int*)(ws + oNOffs);
    int*   EOffs = (int*)(ws + oEOffs);
    int*   NCnt  = (int*)(ws + oNCnt);
    int*   ECnt  = (int*)(ws + oECnt);
    int*   NOrd  = (int*)(ws + oNOrd);
    int*   EOrd  = (int*)(ws + oEOrd);
    float* Dinv  = (float*)(ws + oDinv);
    float* Bnorm = (float*)(ws + oBnorm);

    const int WN = D_ * D_;
    __hip_bfloat16* WtHG = Wt;
    __hip_bfloat16* WtQ  = Wt + (size_t)WN;
    __hip_bfloat16* WtK  = Wt + (size_t)2 * WN;
    __hip_bfloat16* WtV  = Wt + (size_t)3 * WN;
    __hip_bfloat16* WtO  = Wt + (size_t)4 * WN;

    // -------- Phase 0: convert+transpose the five weight matrices -----------
    {
        dim3 g(8, 8, 1);
        wt_transpose_kernel<<<g, 256, 0, stream>>>(W_hg, WtHG);
        wt_transpose_kernel<<<g, 256, 0, stream>>>(WQ,   WtQ);
        wt_transpose_kernel<<<g, 256, 0, stream>>>(WK,   WtK);
        wt_transpose_kernel<<<g, 256, 0, stream>>>(WV,   WtV);
        wt_transpose_kernel<<<g, 256, 0, stream>>>(WO,   WtO);
    }

    // -------- Phase 1: hypergraph conv per modality -> Hbf[md] --------------
    for (int md = 0; md < 3; md++) {
        const int* nidx = hidx[md];
        const int* eidx = hidx[md] + C_;
        __hip_bfloat16* hbf = Hbf + (size_t)md * BN_ * D_;

        cvt_kernel<<<(BN_ * D_) / 256, 256, 0, stream>>>(xin[md], Tmp, BN_ * D_);

        zero_kernel<<<(zeroWords + 255) / 256, 256, 0, stream>>>((float*)(ws + oZero), zeroWords);
        hg_count_kernel<<<C_ / 256, 256, 0, stream>>>(nidx, eidx, Ddeg, Edeg);
        hg_scan_kernel<<<1, N_, 0, stream>>>(Ddeg, NOffs, Dinv, NCnt, N_);
        hg_scan_kernel<<<1, M_, 0, stream>>>(Edeg, EOffs, Bnorm, ECnt, M_);
        hg_fill_kernel<<<C_ / 256, 256, 0, stream>>>(nidx, eidx, NOffs, EOffs, NCnt, ECnt, NOrd, EOrd);

        // xp = x @ W_hg (fp32 out)
        launch_gemm(stream, Tmp, D_, 0, WtHG, D_, 0, Xp, D_, 0, 0,
                    BN_, D_, D_, 1, 1.0f, nullptr, nullptr, 0, 0);

        hg_s12_kernel<<<BN_, 64, 0, stream>>>(Xp, att_hg, S1, S2);
        hg_edge_s2_kernel<<<(C_ * B_) / 256, 256, 0, stream>>>(nidx, eidx, S2, Es2);
        hg_node_softmax_kernel<<<N_, 256, 0, stream>>>(eidx, NOffs, NOrd, S1, Es2, EE, Inv);
        hg_xedge_kernel<<<M_ * B_, 256, 0, stream>>>(nidx, EOffs, EOrd, EE, Inv, Xp, Bnorm, Xe);
        hg_xnode_kernel<<<N_ * B_, 256, 0, stream>>>(eidx, NOffs, NOrd, EE, Inv, Xe, Dinv, hbf);
    }

    // -------- Phase 2: K, V projections (V stored transposed per batch) -----
    for (int n = 0; n < 3; n++) {
        const __hip_bfloat16* hn = Hbf + (size_t)n * BN_ * D_;
        launch_gemm(stream, hn, D_, 0, WtK, D_, 0, Kbf + (size_t)n * BN_ * D_, D_, 0, 0,
                    BN_, D_, D_, 1, 1.0f, bK, nullptr, 1, 0);
        launch_gemm(stream, hn, D_, 0, WtV, D_, 0, Tmp, D_, 0, 0,
                    BN_, D_, D_, 1, 1.0f, bV, nullptr, 1, 0);
        transpose_bf16_kernel<<<dim3(N_ / 32, D_ / 32, B_), 256, 0, stream>>>(
            Tmp, Vt + (size_t)n * BN_ * D_, N_, D_, (long long)N_ * D_, (long long)D_ * N_);
    }

    // -------- Phase 3: cross-modal attention + output -----------------------
    for (int m = 0; m < 3; m++) {
        const __hip_bfloat16* hm = Hbf + (size_t)m * BN_ * D_;
        launch_gemm(stream, hm, D_, 0, WtQ, D_, 0, Qbf, D_, 0, 0,
                    BN_, D_, D_, 1, 1.0f, bQ, nullptr, 1, 0);
        int cnt = 0;
        for (int n = 0; n < 3; n++) {
            if (n == m) continue;
            for (int cb = 0; cb < B_; cb += CB_) {
                // S = scale * Q @ K^T   (CB_ batches, fp32)
                launch_gemm(stream, Qbf + (size_t)cb * N_ * D_, D_, (long long)N_ * D_,
                            Kbf + (size_t)n * BN_ * D_ + (size_t)cb * N_ * D_, D_, (long long)N_ * D_,
                            Sf, N_, (long long)N_ * N_, 0,
                            N_, N_, D_, CB_, 0.0625f, nullptr, nullptr, 0, 0);
                attn_softmax_kernel<<<CB_ * N_, 256, 0, stream>>>(Sf);
                // msg (+)= P @ V
                launch_gemm(stream, Sf, 2 * N_, (long long)2 * N_ * N_,
                            Vt + (size_t)n * BN_ * D_ + (size_t)cb * D_ * N_, N_, (long long)D_ * N_,
                            Msg + (size_t)cb * N_ * D_, D_, (long long)N_ * D_, 0,
                            N_, D_, N_, CB_, 1.0f, nullptr, nullptr, 3, cnt);
            }
            cnt++;
        }
        // out_m = relu(h_m @ WO + bO + msg) -> fp32 at element offset m*BN*D
        launch_gemm(stream, hm, D_, 0, WtO, D_, 0,
                    outp, D_, 0, (long long)m * BN_ * D_,
                    BN_, D_, D_, 1, 1.0f, bO, Msg, 2, 0);
    }
}

// Round 5
// 1467.248 us; speedup vs baseline: 2.1026x; 2.1026x over previous
//
#include <hip/hip_runtime.h>
#include <hip/hip_bf16.h>
#include <stdint.h>

// ---------------------------------------------------------------------------
// B=16, N=1024, D=256, M=128, C=8192. fp32 in/out, bf16 MFMA internally.
// Output: 3 x [B,N,D] fp32 concatenated.
// ---------------------------------------------------------------------------

namespace {
constexpr int B_ = 16;
constexpr int N_ = 1024;
constexpr int D_ = 256;
constexpr int M_ = 128;
constexpr int C_ = 8192;
constexpr int BN_ = B_ * N_;                       // 16384
constexpr long long BND_ = (long long)BN_ * D_;    // 4,194,304 elems
constexpr int NB_ = N_ * B_;                       // 16384
}

typedef short bf16x8_t __attribute__((ext_vector_type(8)));
typedef float f32x4_t __attribute__((ext_vector_type(4)));

#define DEV static __device__ __forceinline__
DEV float bf2f(unsigned short u) { return __uint_as_float((unsigned)u << 16); }
DEV unsigned short f2bf_bits(float x) { return __builtin_bit_cast(unsigned short, __float2bfloat16(x)); }

// ---------------------------------------------------------------------------
// NT bf16 MFMA GEMM, 128x128 tile, BK=32, 4 waves, software-pipelined staging.
// epi: 0 = fp32 C = v*scale
//      1 = bf16 C = v*scale + bias[col]       (bias fp32, nullable)
//      2 = fp32 C[cOff+idx] = relu(v + bias[col] + addp[idx] + addp2[idx])
// ---------------------------------------------------------------------------
__global__ __launch_bounds__(256) void gemm_nt_kernel(
    const __hip_bfloat16* __restrict__ Abf, int lda, long long sA,
    const __hip_bfloat16* __restrict__ Btbf, int ldb, long long sB,
    void* __restrict__ Cv, int ldc, long long sC, long long cOff,
    int K, float scale,
    const float* __restrict__ bias,
    const float* __restrict__ addp, const float* __restrict__ addp2,
    int epi)
{
    __shared__ __align__(16) short smA[128 * 32];
    __shared__ __align__(16) short smB[128 * 32];

    const int tid = threadIdx.x;
    const int wid = tid >> 6;
    const int lane = tid & 63;
    const size_t bz = blockIdx.z;

    const short* Ab = (const short*)Abf + bz * (size_t)sA + (size_t)blockIdx.x * 128 * lda;
    const short* Bb = (const short*)Btbf + bz * (size_t)sB + (size_t)blockIdx.y * 128 * ldb;

    const int wm = (wid >> 1) * 64;
    const int wn = (wid & 1) * 64;
    const int fr = lane & 15;            // fragment row (m or n)
    const int kq = (lane >> 4) * 8;      // k-offset of this lane's 8 elems
    const int sr = tid >> 2;             // staging row 0..63 (plus h*64)
    const int sc = (tid & 3) * 8;        // staging short-col

    f32x4_t acc[4][4] = {};
    int4 avv[2], bvv[2];
#pragma unroll
    for (int h = 0; h < 2; h++) {        // prologue: tile 0
        const int row = h * 64 + sr;
        avv[h] = *(const int4*)(Ab + (size_t)row * lda + sc);
        bvv[h] = *(const int4*)(Bb + (size_t)row * ldb + sc);
    }

    for (int k0 = 0; k0 < K; k0 += 32) {
        __syncthreads();                 // prior tile's ds_reads complete
#pragma unroll
        for (int h = 0; h < 2; h++) {
            const int row = h * 64 + sr;
            *(int4*)&smA[row * 32 + sc] = avv[h];
            *(int4*)&smB[row * 32 + sc] = bvv[h];
        }
        __syncthreads();

        const int kn = k0 + 32;          // prefetch next tile (overlaps MFMA)
        if (kn < K) {
#pragma unroll
            for (int h = 0; h < 2; h++) {
                const int row = h * 64 + sr;
                avv[h] = *(const int4*)(Ab + (size_t)row * lda + (kn + sc));
                bvv[h] = *(const int4*)(Bb + (size_t)row * ldb + (kn + sc));
            }
        }

        bf16x8_t af[4], bfv[4];
#pragma unroll
        for (int i = 0; i < 4; i++)
            af[i] = *(const bf16x8_t*)&smA[(wm + i * 16 + fr) * 32 + kq];
#pragma unroll
        for (int j = 0; j < 4; j++)
            bfv[j] = *(const bf16x8_t*)&smB[(wn + j * 16 + fr) * 32 + kq];
#pragma unroll
        for (int i = 0; i < 4; i++)
#pragma unroll
            for (int j = 0; j < 4; j++)
                acc[i][j] = __builtin_amdgcn_mfma_f32_16x16x32_bf16(af[i], bfv[j], acc[i][j], 0, 0, 0);
    }

    const int rb = (lane >> 4) * 4;
#pragma unroll
    for (int j = 0; j < 4; j++) {
        const int col = blockIdx.y * 128 + wn + j * 16 + fr;
        const float bv = bias ? bias[col] : 0.0f;
#pragma unroll
        for (int i = 0; i < 4; i++) {
#pragma unroll
            for (int r = 0; r < 4; r++) {
                const int row = blockIdx.x * 128 + wm + i * 16 + rb + r;
                const size_t idx = bz * (size_t)sC + (size_t)row * ldc + col;
                const float v = acc[i][j][r] * scale;
                if (epi == 0) {
                    ((float*)Cv)[idx] = v;
                } else if (epi == 1) {
                    ((__hip_bfloat16*)Cv)[idx] = __float2bfloat16(v + bv);
                } else {
                    float o = v + bv + addp[idx] + addp2[idx];
                    ((float*)Cv)[(size_t)cOff + idx] = o > 0.0f ? o : 0.0f;
                }
            }
        }
    }
}

// ---------------------------------------------------------------------------
// Weight convert+transpose, all 5 weights in one dispatch (z selects).
// ---------------------------------------------------------------------------
__global__ __launch_bounds__(256) void wt_transpose_kernel(
    const float* __restrict__ W0, const float* __restrict__ W1,
    const float* __restrict__ W2, const float* __restrict__ W3,
    const float* __restrict__ W4, __hip_bfloat16* __restrict__ out)
{
    const int z = blockIdx.z;
    const float* in = z == 0 ? W0 : z == 1 ? W1 : z == 2 ? W2 : z == 3 ? W3 : W4;
    __hip_bfloat16* o = out + (size_t)z * D_ * D_;
    __shared__ float t[32][33];
    const int r0 = blockIdx.x * 32, c0 = blockIdx.y * 32;
    const int tx = threadIdx.x & 31, ty = threadIdx.x >> 5;
#pragma unroll
    for (int k = 0; k < 4; k++) {
        int r = ty + k * 8;
        t[r][tx] = in[(size_t)(r0 + r) * D_ + (c0 + tx)];
    }
    __syncthreads();
#pragma unroll
    for (int k = 0; k < 4; k++) {
        int r = ty + k * 8;
        o[(size_t)(c0 + r) * D_ + (r0 + tx)] = __float2bfloat16(t[tx][r]);
    }
}

// bf16 transpose for V: out[c][r] = in[r][c], batched over z.
__global__ __launch_bounds__(256) void transpose_bf16_kernel(
    const __hip_bfloat16* __restrict__ in, __hip_bfloat16* __restrict__ out,
    int R, int Cc, long long sIn, long long sOut)
{
    __shared__ short t[32][33];
    const size_t bz = blockIdx.z;
    const short* I = (const short*)in + bz * (size_t)sIn;
    short* O = (short*)out + bz * (size_t)sOut;
    const int r0 = blockIdx.x * 32, c0 = blockIdx.y * 32;
    const int tx = threadIdx.x & 31, ty = threadIdx.x >> 5;
#pragma unroll
    for (int k = 0; k < 4; k++) {
        int r = ty + k * 8;
        t[r][tx] = I[(size_t)(r0 + r) * Cc + (c0 + tx)];
    }
    __syncthreads();
#pragma unroll
    for (int k = 0; k < 4; k++) {
        int r = ty + k * 8;
        O[(size_t)(c0 + r) * R + (r0 + tx)] = t[tx][r];
    }
}

// all 3 modality inputs fp32 -> bf16, one dispatch
__global__ void cvt3_kernel(const float* __restrict__ x0, const float* __restrict__ x1,
                            const float* __restrict__ x2, __hip_bfloat16* __restrict__ dst)
{
    const int z = blockIdx.z;
    const float* s = z == 0 ? x0 : z == 1 ? x1 : x2;
    const long long i = (long long)blockIdx.x * 256 + threadIdx.x;
    dst[(size_t)z * BND_ + i] = __float2bfloat16(s[i]);
}

__global__ void zero_kernel(float* __restrict__ p, int n)
{
    const int i = blockIdx.x * 256 + threadIdx.x;
    if (i < n) p[i] = 0.0f;
}

// ---------------------------------------------------------------------------
// Hypergraph pipeline, batched over 3 modalities via blockIdx.z
// ---------------------------------------------------------------------------
__global__ void hg_count_kernel(const int* __restrict__ i0, const int* __restrict__ i1,
                                const int* __restrict__ i2,
                                int* __restrict__ Ddeg, int* __restrict__ Edeg)
{
    const int z = blockIdx.z;
    const int* idx = z == 0 ? i0 : z == 1 ? i1 : i2;
    const int c = blockIdx.x * 256 + threadIdx.x;
    atomicAdd(&Ddeg[z * N_ + idx[c]], 1);
    atomicAdd(&Edeg[z * M_ + idx[C_ + c]], 1);
}

__global__ __launch_bounds__(1024) void hg_scan_kernel(
    const int* __restrict__ deg, int* __restrict__ offs,
    float* __restrict__ inv, int* __restrict__ cnt, int len)
{
    const int z = blockIdx.z;
    deg += z * len; offs += z * (len + 1); inv += z * len; cnt += z * len;
    __shared__ int tmp[1024];
    const int t = threadIdx.x;
    const int v = deg[t];
    tmp[t] = v;
    __syncthreads();
    for (int o = 1; o < len; o <<= 1) {
        int x = (t >= o) ? tmp[t - o] : 0;
        __syncthreads();
        tmp[t] += x;
        __syncthreads();
    }
    offs[t] = tmp[t] - v;
    if (t == len - 1) offs[len] = tmp[t];
    inv[t] = (v > 0) ? (1.0f / (float)v) : 0.0f;
    cnt[t] = 0;
}

__global__ void hg_fill_kernel(const int* __restrict__ i0, const int* __restrict__ i1,
                               const int* __restrict__ i2,
                               const int* __restrict__ noffs, const int* __restrict__ eoffs,
                               int* __restrict__ ncnt, int* __restrict__ ecnt,
                               int* __restrict__ nord, int* __restrict__ eord)
{
    const int z = blockIdx.z;
    const int* nidx = z == 0 ? i0 : z == 1 ? i1 : i2;
    const int* eidx = nidx + C_;
    noffs += z * (N_ + 1); eoffs += z * (M_ + 1);
    ncnt += z * N_; ecnt += z * M_; nord += z * C_; eord += z * C_;
    const int c = blockIdx.x * 256 + threadIdx.x;
    const int nd = nidx[c], ed = eidx[c];
    const int p1 = atomicAdd(&ncnt[nd], 1);
    nord[noffs[nd] + p1] = c;
    const int p2 = atomicAdd(&ecnt[ed], 1);
    eord[eoffs[ed] + p2] = c;
}

// s1/s2 from bf16 xp; one wave per (md,b,n)
__global__ __launch_bounds__(64) void hg_s12_kernel(
    const unsigned short* __restrict__ Xp, const float* __restrict__ att,
    float* __restrict__ s1, float* __restrict__ s2)
{
    const int z = blockIdx.z;
    const int bid = blockIdx.x;
    const int b = bid >> 10;
    const int n = bid & (N_ - 1);
    const int lane = threadIdx.x;
    const unsigned short* xr = Xp + (size_t)z * BND_ + (size_t)(b * N_ + n) * D_;
    const ushort4 u = ((const ushort4*)xr)[lane];
    const float4 a1 = ((const float4*)att)[lane];
    const float4 a2 = ((const float4*)(att + D_))[lane];
    float d1 = bf2f(u.x) * a1.x + bf2f(u.y) * a1.y + bf2f(u.z) * a1.z + bf2f(u.w) * a1.w;
    float d2 = bf2f(u.x) * a2.x + bf2f(u.y) * a2.y + bf2f(u.z) * a2.z + bf2f(u.w) * a2.w;
#pragma unroll
    for (int o = 32; o > 0; o >>= 1) { d1 += __shfl_down(d1, o); d2 += __shfl_down(d2, o); }
    if (lane == 0) { s1[z * NB_ + n * 16 + b] = d1; s2[z * NB_ + n * 16 + b] = d2; }
}

__global__ void hg_edge_s2_kernel(const int* __restrict__ i0, const int* __restrict__ i1,
                                  const int* __restrict__ i2,
                                  const float* __restrict__ s2, float* __restrict__ edge_s2)
{
    const int z = blockIdx.z;
    const int* nidx = z == 0 ? i0 : z == 1 ? i1 : i2;
    const int* eidx = nidx + C_;
    const int i = blockIdx.x * 256 + threadIdx.x;   // C*B
    const int c = i >> 4, b = i & 15;
    atomicAdd(&edge_s2[z * M_ * 16 + eidx[c] * 16 + b], s2[z * NB_ + nidx[c] * 16 + b]);
}

__global__ __launch_bounds__(256) void hg_node_softmax_kernel(
    const int* __restrict__ i0, const int* __restrict__ i1, const int* __restrict__ i2,
    const int* __restrict__ noffs, const int* __restrict__ nord,
    const float* __restrict__ s1, const float* __restrict__ edge_s2,
    float* __restrict__ ee, float* __restrict__ inv_sum)
{
    const int z = blockIdx.z;
    const int* eidx = (z == 0 ? i0 : z == 1 ? i1 : i2) + C_;
    noffs += z * (N_ + 1); nord += z * C_;
    s1 += z * NB_; edge_s2 += (size_t)z * M_ * 16;
    ee += (size_t)z * C_ * 16; inv_sum += z * NB_;

    const int n = blockIdx.x;
    const int base = noffs[n];
    const int len = noffs[n + 1] - base;
    if (len == 0) return;
    const int cp = threadIdx.x >> 4;
    const int b = threadIdx.x & 15;
    __shared__ float red[16][16];
    const float s1nb = s1[n * 16 + b];

    float mx = -1e30f;
    for (int i = cp; i < len; i += 16) {
        int c = nord[base + i];
        float e = s1nb + edge_s2[eidx[c] * 16 + b];
        e = e > 0.0f ? e : 0.2f * e;      // leaky_relu 0.2
        mx = fmaxf(mx, e);
    }
    red[cp][b] = mx;
    __syncthreads();
    for (int s = 8; s > 0; s >>= 1) {
        if (cp < s) red[cp][b] = fmaxf(red[cp][b], red[cp + s][b]);
        __syncthreads();
    }
    mx = red[0][b];
    __syncthreads();

    float sm = 0.0f;
    for (int i = cp; i < len; i += 16) {
        int c = nord[base + i];
        float e = s1nb + edge_s2[eidx[c] * 16 + b];
        e = e > 0.0f ? e : 0.2f * e;
        float ex = __expf(e - mx);
        ee[c * 16 + b] = ex;
        sm += ex;
    }
    red[cp][b] = sm;
    __syncthreads();
    for (int s = 8; s > 0; s >>= 1) {
        if (cp < s) red[cp][b] += red[cp + s][b];
        __syncthreads();
    }
    if (cp == 0) inv_sum[n * 16 + b] = 1.0f / (red[0][b] + 1e-16f);
}

__global__ __launch_bounds__(256) void hg_xedge_kernel(
    const int* __restrict__ i0, const int* __restrict__ i1, const int* __restrict__ i2,
    const int* __restrict__ eoffs, const int* __restrict__ eord,
    const float* __restrict__ ee, const float* __restrict__ inv_sum,
    const unsigned short* __restrict__ Xp, const float* __restrict__ Bnorm,
    float* __restrict__ x_edge)
{
    const int z = blockIdx.z;
    const int* nidx = z == 0 ? i0 : z == 1 ? i1 : i2;
    eoffs += z * (M_ + 1); eord += z * C_;
    ee += (size_t)z * C_ * 16; inv_sum += z * NB_;
    const unsigned short* xp = Xp + (size_t)z * BND_;
    Bnorm += z * M_; x_edge += (size_t)z * M_ * B_ * D_;

    const int m = blockIdx.x >> 4;
    const int b = blockIdx.x & 15;
    const int d = threadIdx.x;
    const int base = eoffs[m];
    const int len = eoffs[m + 1] - base;
    float acc = 0.0f;
    for (int i = 0; i < len; i++) {
        int c = eord[base + i];
        int nd = nidx[c];
        float coeff = ee[c * 16 + b] * inv_sum[nd * 16 + b];
        acc += coeff * bf2f(xp[(size_t)(b * N_ + nd) * D_ + d]);
    }
    x_edge[((size_t)(m * 16 + b)) * D_ + d] = Bnorm[m] * acc;
}

__global__ __launch_bounds__(256) void hg_xnode_kernel(
    const int* __restrict__ i0, const int* __restrict__ i1, const int* __restrict__ i2,
    const int* __restrict__ noffs, const int* __restrict__ nord,
    const float* __restrict__ ee, const float* __restrict__ inv_sum,
    const float* __restrict__ x_edge, const float* __restrict__ Dinv,
    __hip_bfloat16* __restrict__ Hbf)
{
    const int z = blockIdx.z;
    const int* eidx = (z == 0 ? i0 : z == 1 ? i1 : i2) + C_;
    noffs += z * (N_ + 1); nord += z * C_;
    ee += (size_t)z * C_ * 16; inv_sum += z * NB_;
    x_edge += (size_t)z * M_ * B_ * D_; Dinv += z * N_;
    __hip_bfloat16* hbf = Hbf + (size_t)z * BND_;

    const int n = blockIdx.x >> 4;
    const int b = blockIdx.x & 15;
    const int d = threadIdx.x;
    const int base = noffs[n];
    const int len = noffs[n + 1] - base;
    float acc = 0.0f;
    const float inv = (len > 0) ? inv_sum[n * 16 + b] : 0.0f;
    for (int i = 0; i < len; i++) {
        int c = nord[base + i];
        float coeff = ee[c * 16 + b] * inv;
        acc += coeff * x_edge[((size_t)(eidx[c] * 16 + b)) * D_ + d];
    }
    hbf[((size_t)(b * N_ + n)) * D_ + d] = __float2bfloat16(Dinv[n] * acc);
}

// ---------------------------------------------------------------------------
// Row softmax over bf16 S (1024 cols), rewritten in place as bf16 P.
// ---------------------------------------------------------------------------
__global__ __launch_bounds__(256) void attn_softmax_kernel(unsigned short* __restrict__ S)
{
    unsigned short* p = S + (size_t)blockIdx.x * 1024;
    const int tid = threadIdx.x;
    const int lane = tid & 63, wid = tid >> 6;
    ushort4 u = ((ushort4*)p)[tid];
    const float v0 = bf2f(u.x), v1 = bf2f(u.y), v2 = bf2f(u.z), v3 = bf2f(u.w);
    __shared__ float red[8];

    float m4 = fmaxf(fmaxf(v0, v1), fmaxf(v2, v3));
#pragma unroll
    for (int o = 32; o > 0; o >>= 1) m4 = fmaxf(m4, __shfl_down(m4, o));
    if (lane == 0) red[wid] = m4;
    __syncthreads();
    const float mx = fmaxf(fmaxf(red[0], red[1]), fmaxf(red[2], red[3]));

    const float e0 = __expf(v0 - mx), e1 = __expf(v1 - mx);
    const float e2 = __expf(v2 - mx), e3 = __expf(v3 - mx);
    float s4 = e0 + e1 + e2 + e3;
#pragma unroll
    for (int o = 32; o > 0; o >>= 1) s4 += __shfl_down(s4, o);
    if (lane == 0) red[4 + wid] = s4;
    __syncthreads();
    const float inv = 1.0f / (red[4] + red[5] + red[6] + red[7]);

    u.x = f2bf_bits(e0 * inv);
    u.y = f2bf_bits(e1 * inv);
    u.z = f2bf_bits(e2 * inv);
    u.w = f2bf_bits(e3 * inv);
    ((ushort4*)p)[tid] = u;
}

// ---------------------------------------------------------------------------
// Host
// ---------------------------------------------------------------------------
static inline void launch_gemm(hipStream_t s,
                               const void* A, int lda, long long sA,
                               const void* Bt, int ldb, long long sB,
                               void* Cv, int ldc, long long sC, long long cOff,
                               int Mrows, int Ncols, int K, int batches,
                               float scale, const float* bias,
                               const float* addp, const float* addp2, int epi)
{
    dim3 g(Mrows / 128, Ncols / 128, batches);
    gemm_nt_kernel<<<g, 256, 0, s>>>((const __hip_bfloat16*)A, lda, sA,
                                     (const __hip_bfloat16*)Bt, ldb, sB,
                                     Cv, ldc, sC, cOff, K, scale,
                                     bias, addp, addp2, epi);
}

extern "C" void kernel_launch(void* const* d_in, const int* in_sizes, int n_in,
                              void* d_out, int out_size, void* d_ws, size_t ws_size,
                              hipStream_t stream)
{
    (void)in_sizes; (void)n_in; (void)out_size; (void)ws_size;

    const float* x0 = (const float*)d_in[0];
    const float* x1 = (const float*)d_in[1];
    const float* x2 = (const float*)d_in[2];
    const int* h0 = (const int*)d_in[3];
    const int* h1 = (const int*)d_in[4];
    const int* h2 = (const int*)d_in[5];
    const float* W_hg  = (const float*)d_in[6];
    const float* att_hg= (const float*)d_in[7];
    const float* WQ = (const float*)d_in[8];
    const float* bQ = (const float*)d_in[9];
    const float* WK = (const float*)d_in[10];
    const float* bK = (const float*)d_in[11];
    const float* WV = (const float*)d_in[12];
    const float* bV = (const float*)d_in[13];
    const float* WO = (const float*)d_in[14];
    const float* bO = (const float*)d_in[15];
    float* outp = (float*)d_out;

    char* ws = (char*)d_ws;
    size_t off = 0;
    auto take = [&](size_t bytes) { size_t r = off; off += (bytes + 255) & ~(size_t)255; return r; };

    const size_t oWt   = take((size_t)5 * D_ * D_ * 2);          // 0.63 MB
    const size_t oHbf  = take((size_t)3 * BND_ * 2);             // 24 MB
    const size_t oKall = take((size_t)3 * BND_ * 2);             // 24 MB
    const size_t oVt   = take((size_t)3 * BND_ * 2);             // 24 MB
    const size_t oQb   = take((size_t)BND_ * 2);                 // 8 MB
    const size_t oBIG  = take((size_t)48 * 1024 * 1024);         // Xc+Xp | Vtmp | S
    const size_t oMsg  = take((size_t)2 * BND_ * 4);             // 32 MB
    const size_t oXe   = take((size_t)3 * M_ * B_ * D_ * 4);     // 6 MB
    const size_t oEE   = take((size_t)3 * C_ * 16 * 4);          // 1.5 MB
    const size_t oS1   = take((size_t)3 * NB_ * 4);
    const size_t oS2   = take((size_t)3 * NB_ * 4);
    const size_t oInv  = take((size_t)3 * NB_ * 4);
    const size_t oZero = take((size_t)3 * (N_ + M_ + M_ * 16) * 4);
    const size_t oNOffs= take((size_t)3 * (N_ + 1) * 4);
    const size_t oEOffs= take((size_t)3 * (M_ + 1) * 4);
    const size_t oNCnt = take((size_t)3 * N_ * 4);
    const size_t oECnt = take((size_t)3 * M_ * 4);
    const size_t oNOrd = take((size_t)3 * C_ * 4);
    const size_t oEOrd = take((size_t)3 * C_ * 4);
    const size_t oDinv = take((size_t)3 * N_ * 4);
    const size_t oBnorm= take((size_t)3 * M_ * 4);

    __hip_bfloat16* Wt   = (__hip_bfloat16*)(ws + oWt);
    __hip_bfloat16* Hbf  = (__hip_bfloat16*)(ws + oHbf);
    __hip_bfloat16* Kall = (__hip_bfloat16*)(ws + oKall);
    __hip_bfloat16* Vt   = (__hip_bfloat16*)(ws + oVt);
    __hip_bfloat16* Qb   = (__hip_bfloat16*)(ws + oQb);
    // BIG union: phase1 Xc (24MB) + Xp (24MB); phase2 Vtmp (24MB); phase3 S (32MB)
    __hip_bfloat16* Xc   = (__hip_bfloat16*)(ws + oBIG);
    __hip_bfloat16* Xp   = (__hip_bfloat16*)(ws + oBIG + (size_t)3 * BND_ * 2);
    __hip_bfloat16* Vtmp = (__hip_bfloat16*)(ws + oBIG);
    __hip_bfloat16* Sb   = (__hip_bfloat16*)(ws + oBIG);
    float* Msg  = (float*)(ws + oMsg);
    float* Xe   = (float*)(ws + oXe);
    float* EE   = (float*)(ws + oEE);
    float* S1f  = (float*)(ws + oS1);
    float* S2f  = (float*)(ws + oS2);
    float* Inv  = (float*)(ws + oInv);
    int*   Ddeg = (int*)(ws + oZero);
    int*   Edeg = (int*)(ws + oZero + (size_t)3 * N_ * 4);
    float* Es2  = (float*)(ws + oZero + (size_t)3 * (N_ + M_) * 4);
    const int zeroWords = 3 * (N_ + M_ + M_ * 16);
    int*   NOffs = (int*)(ws + oNOffs);
    int*   EOffs = (int*)(ws + oEOffs);
    int*   NCnt  = (int*)(ws + oNCnt);
    int*   ECnt  = (int*)(ws + oECnt);
    int*   NOrd  = (int*)(ws + oNOrd);
    int*   EOrd  = (int*)(ws + oEOrd);
    float* Dinv  = (float*)(ws + oDinv);
    float* Bnorm = (float*)(ws + oBnorm);

    const int WN = D_ * D_;
    __hip_bfloat16* WtHG = Wt;
    __hip_bfloat16* WtQ  = Wt + (size_t)WN;
    __hip_bfloat16* WtK  = Wt + (size_t)2 * WN;
    __hip_bfloat16* WtV  = Wt + (size_t)3 * WN;
    __hip_bfloat16* WtO  = Wt + (size_t)4 * WN;

    // -------- Phase 0: weights (one dispatch) -------------------------------
    wt_transpose_kernel<<<dim3(8, 8, 5), 256, 0, stream>>>(W_hg, WQ, WK, WV, WO, Wt);

    // -------- Phase 1: hypergraph conv, all modalities batched --------------
    cvt3_kernel<<<dim3((unsigned)(BND_ / 256), 1, 3), 256, 0, stream>>>(x0, x1, x2, Xc);
    zero_kernel<<<(zeroWords + 255) / 256, 256, 0, stream>>>((float*)(ws + oZero), zeroWords);
    hg_count_kernel<<<dim3(C_ / 256, 1, 3), 256, 0, stream>>>(h0, h1, h2, Ddeg, Edeg);
    hg_scan_kernel<<<dim3(1, 1, 3), N_, 0, stream>>>(Ddeg, NOffs, Dinv, NCnt, N_);
    hg_scan_kernel<<<dim3(1, 1, 3), M_, 0, stream>>>(Edeg, EOffs, Bnorm, ECnt, M_);
    hg_fill_kernel<<<dim3(C_ / 256, 1, 3), 256, 0, stream>>>(h0, h1, h2, NOffs, EOffs,
                                                             NCnt, ECnt, NOrd, EOrd);
    // xp = x @ W_hg  -> bf16, z=3
    launch_gemm(stream, Xc, D_, BND_, WtHG, D_, 0, Xp, D_, BND_, 0,
                BN_, D_, D_, 3, 1.0f, nullptr, nullptr, nullptr, 1);
    hg_s12_kernel<<<dim3(BN_, 1, 3), 64, 0, stream>>>((const unsigned short*)Xp, att_hg, S1f, S2f);
    hg_edge_s2_kernel<<<dim3(C_ * B_ / 256, 1, 3), 256, 0, stream>>>(h0, h1, h2, S2f, Es2);
    hg_node_softmax_kernel<<<dim3(N_, 1, 3), 256, 0, stream>>>(h0, h1, h2, NOffs, NOrd,
                                                               S1f, Es2, EE, Inv);
    hg_xedge_kernel<<<dim3(M_ * B_, 1, 3), 256, 0, stream>>>(h0, h1, h2, EOffs, EOrd, EE, Inv,
                                                             (const unsigned short*)Xp, Bnorm, Xe);
    hg_xnode_kernel<<<dim3(N_ * B_, 1, 3), 256, 0, stream>>>(h0, h1, h2, NOffs, NOrd, EE, Inv,
                                                             Xe, Dinv, Hbf);

    // -------- Phase 2: K, V for all 3 modalities ----------------------------
    launch_gemm(stream, Hbf, D_, 0, WtK, D_, 0, Kall, D_, 0, 0,
                3 * BN_, D_, D_, 1, 1.0f, bK, nullptr, nullptr, 1);
    launch_gemm(stream, Hbf, D_, 0, WtV, D_, 0, Vtmp, D_, 0, 0,
                3 * BN_, D_, D_, 1, 1.0f, bV, nullptr, nullptr, 1);
    transpose_bf16_kernel<<<dim3(N_ / 32, D_ / 32, 48), 256, 0, stream>>>(
        Vtmp, Vt, N_, D_, (long long)N_ * D_, (long long)D_ * N_);

    // -------- Phase 3: cross-modal attention + output -----------------------
    for (int m = 0; m < 3; m++) {
        const __hip_bfloat16* hm = Hbf + (size_t)m * BND_;
        launch_gemm(stream, hm, D_, 0, WtQ, D_, 0, Qb, D_, 0, 0,
                    BN_, D_, D_, 1, 1.0f, bQ, nullptr, nullptr, 1);
        const int partners[2] = {m == 0 ? 1 : 0, m == 2 ? 1 : 2};
        for (int pi = 0; pi < 2; pi++) {
            const int pn = partners[pi];
            // S = (1/16) Q @ K^T  -> bf16, all 16 batches (grid 8x8x16)
            launch_gemm(stream, Qb, D_, (long long)N_ * D_,
                        Kall + (size_t)pn * BND_, D_, (long long)N_ * D_,
                        Sb, N_, (long long)N_ * N_, 0,
                        N_, N_, D_, B_, 0.0625f, nullptr, nullptr, nullptr, 1);
            attn_softmax_kernel<<<B_ * N_, 256, 0, stream>>>((unsigned short*)Sb);
            // Msg[pi] = P @ V   (grid 8x2x16, fp32)
            launch_gemm(stream, Sb, N_, (long long)N_ * N_,
                        Vt + (size_t)pn * BND_, N_, (long long)D_ * N_,
                        Msg + (size_t)pi * BND_, D_, (long long)N_ * D_, 0,
                        N_, D_, N_, B_, 1.0f, nullptr, nullptr, nullptr, 0);
        }
        // out_m = relu(h_m @ WO + bO + Msg0 + Msg1) -> fp32
        launch_gemm(stream, hm, D_, 0, WtO, D_, 0,
                    outp, D_, 0, (long long)m * BND_,
                    BN_, D_, D_, 1, 1.0f, bO, Msg, Msg + BND_, 2);
    }
}